// Round 1
// baseline (569.816 us; speedup 1.0000x reference)
//
#include <hip/hip_runtime.h>
#include <math.h>

#define NAG 6
#define CC  64
#define HH  128
#define WW  128
#define HWT 16384
#define BN_EPS 1e-5f

typedef unsigned int u32;

__device__ __forceinline__ float gelu_exact(float x) {
    return 0.5f * x * (1.0f + erff(x * 0.7071067811865476f));
}

// ---------------- init min/max slots ----------------
__global__ void k_init(u32* __restrict__ mm) {
    int t = threadIdx.x;
    if (t < NAG) mm[t] = 0x7F800000u;        // +inf (min slots)
    else if (t < 2 * NAG) mm[t] = 0u;        // 0    (max slots; h2 >= 0)
}

// ---------------- confidence maps (pre-normalization) + per-agent min/max ----------------
__global__ __launch_bounds__(256) void k_conf(
    const float* __restrict__ raw,
    const float* __restrict__ w1, const float* __restrict__ b1,
    const float* __restrict__ gamma, const float* __restrict__ beta,
    const float* __restrict__ mean, const float* __restrict__ var,
    const float* __restrict__ w2, const float* __restrict__ b2,
    float* __restrict__ conf, u32* __restrict__ mm)
{
    const int n = blockIdx.y;
    const int p = blockIdx.x * 256 + threadIdx.x;
    const float* x = raw + (size_t)(n * CC) * HWT + p;

    float a[4] = {0.f, 0.f, 0.f, 0.f};
    #pragma unroll 8
    for (int c = 0; c < CC; ++c) {
        float v = x[c * HWT];
        a[0] = fmaf(w1[0 * CC + c], v, a[0]);
        a[1] = fmaf(w1[1 * CC + c], v, a[1]);
        a[2] = fmaf(w1[2 * CC + c], v, a[2]);
        a[3] = fmaf(w1[3 * CC + c], v, a[3]);
    }
    float h2 = b2[0];
    #pragma unroll
    for (int o = 0; o < 4; ++o) {
        float sc = gamma[o] * rsqrtf(var[o] + BN_EPS);
        float hb = (a[o] + b1[o] - mean[o]) * sc + beta[o];
        hb = fmaxf(hb, 0.f);
        h2 = fmaf(w2[o], hb, h2);
    }
    h2 = fmaxf(h2, 0.f);
    conf[n * HWT + p] = h2;

    // block reduction, then one atomic per block (uint order == float order for x>=0)
    float mn = h2, mx = h2;
    #pragma unroll
    for (int off = 32; off > 0; off >>= 1) {
        mn = fminf(mn, __shfl_xor(mn, off, 64));
        mx = fmaxf(mx, __shfl_xor(mx, off, 64));
    }
    __shared__ float smn[4], smx[4];
    int wid = threadIdx.x >> 6, lane = threadIdx.x & 63;
    if (lane == 0) { smn[wid] = mn; smx[wid] = mx; }
    __syncthreads();
    if (threadIdx.x == 0) {
        mn = fminf(fminf(smn[0], smn[1]), fminf(smn[2], smn[3]));
        mx = fmaxf(fmaxf(smx[0], smx[1]), fmaxf(smx[2], smx[3]));
        atomicMin(&mm[n], __float_as_uint(mn));
        atomicMax(&mm[n + NAG], __float_as_uint(mx));
    }
}

// ---------------- min-max normalize in place ----------------
__global__ __launch_bounds__(256) void k_norm(float* __restrict__ conf,
                                              const u32* __restrict__ mm)
{
    const int n = blockIdx.y;
    const int p = blockIdx.x * 256 + threadIdx.x;
    const float mn = __uint_as_float(mm[n]);
    const float mx = __uint_as_float(mm[n + NAG]);
    const float inv = 1.f / (mx - mn);
    conf[n * HWT + p] = (conf[n * HWT + p] - mn) * inv;
}

// ---------------- P = A1*raw, Q = A2*raw, V = Vw*raw + vb ----------------
// blockIdx: x = pixel block (256 px), y = agent, z = matrix (0:P, 1:Q, 2:V)
__global__ __launch_bounds__(256) void k_pqv(
    const float* __restrict__ raw, const float* __restrict__ a1w,
    const float* __restrict__ vw, const float* __restrict__ vb,
    float* __restrict__ P, float* __restrict__ Q, float* __restrict__ V)
{
    const int n = blockIdx.y;
    const int m = blockIdx.z;
    const int og = __builtin_amdgcn_readfirstlane(threadIdx.x >> 6); // wave-uniform -> SGPR
    const int pg = threadIdx.x & 63;
    const int px = blockIdx.x * 256 + pg * 4;

    const float* wbase;
    int wstride;
    float* out;
    if (m == 0)      { wbase = a1w;      wstride = 2 * CC; out = P; }
    else if (m == 1) { wbase = a1w + CC; wstride = 2 * CC; out = Q; }
    else             { wbase = vw;       wstride = CC;     out = V; }

    const float* xb = raw + (size_t)(n * CC) * HWT + px;

    float acc[16][4];
    #pragma unroll
    for (int j = 0; j < 16; ++j)
        for (int q = 0; q < 4; ++q) acc[j][q] = 0.f;

    #pragma unroll 4
    for (int c = 0; c < CC; ++c) {
        float4 x = *(const float4*)(xb + (size_t)c * HWT);
        #pragma unroll
        for (int j = 0; j < 16; ++j) {
            float w = wbase[(og * 16 + j) * wstride + c];   // scalar (s_load): og uniform
            acc[j][0] = fmaf(w, x.x, acc[j][0]);
            acc[j][1] = fmaf(w, x.y, acc[j][1]);
            acc[j][2] = fmaf(w, x.z, acc[j][2]);
            acc[j][3] = fmaf(w, x.w, acc[j][3]);
        }
    }

    #pragma unroll
    for (int j = 0; j < 16; ++j) {
        int o = og * 16 + j;
        float bias = (m == 2) ? vb[o] : 0.f;
        float4 r = make_float4(acc[j][0] + bias, acc[j][1] + bias,
                               acc[j][2] + bias, acc[j][3] + bias);
        *(float4*)(out + (size_t)(n * CC + o) * HWT + px) = r;
    }
}

// ---------------- main: S[i,c] = sum_k dwconv11(gelu(P_i+Q_k+b)) * V_k * att_ik ----------------
#define TS 64            // output tile side
#define GP 76            // LDS tile pitch (floats)
#define GR 74            // LDS tile rows (64 + 2*5)
#define GN (GR * GP)     // 5624
#define NU 22            // ceil(GN / 256)

__global__ __launch_bounds__(256) void k_main(
    const float* __restrict__ P, const float* __restrict__ Q,
    const float* __restrict__ V, const float* __restrict__ conf,
    const float* __restrict__ a1b, const float* __restrict__ dww,
    const float* __restrict__ dwb, float* __restrict__ S)
{
    const int tile = blockIdx.x;              // 0..3
    const int c    = blockIdx.y;              // 0..63
    const int i    = blockIdx.z;              // 0..5
    const int y0 = (tile >> 1) * TS;
    const int x0 = (tile & 1) * TS;
    const int t  = threadIdx.x;
    const int r0  = (t >> 4) * 4;             // thread's 4 output rows (within tile)
    const int px0 = (t & 15) * 4;             // thread's 4 output cols (within tile)

    __shared__ float GT[GN];

    const float ba1 = a1b[c];
    const float bdw = dwb[c];
    const float* wr = dww + c * 121;          // block-uniform -> scalar loads

    // preload halo'd P tile into registers (+ global offsets; -1 = zero-pad)
    float preg[NU];
    int   offs[NU];
    const float* Pc = P + (size_t)(i * CC + c) * HWT;
    #pragma unroll
    for (int u = 0; u < NU; ++u) {
        int idx = t + u * 256;
        int row = idx / GP, col = idx - row * GP;
        int gy = y0 + row - 5, gx = x0 + col - 5;
        bool inb = (idx < GN) && (col < GR) &&
                   (gy >= 0) && (gy < HH) && (gx >= 0) && (gx < WW);
        offs[u] = inb ? (gy * WW + gx) : -1;
        preg[u] = inb ? Pc[gy * WW + gx] : 0.f;
    }

    // preload (1 - conf_i) for this thread's 16 output pixels
    float omci[4][4];
    const float* cfi = conf + i * HWT;
    #pragma unroll
    for (int j = 0; j < 4; ++j) {
        int y = y0 + r0 + j;
        float4 cv = *(const float4*)(cfi + y * WW + x0 + px0);
        omci[j][0] = 1.f - cv.x; omci[j][1] = 1.f - cv.y;
        omci[j][2] = 1.f - cv.z; omci[j][3] = 1.f - cv.w;
    }

    float sacc[4][4];
    #pragma unroll
    for (int j = 0; j < 4; ++j)
        for (int q = 0; q < 4; ++q) sacc[j][q] = 0.f;

    for (int k = 0; k < NAG; ++k) {
        // stage gelu(P + Q + b) tile to LDS (zero outside image = SAME padding)
        const float* Qc = Q + (size_t)(k * CC + c) * HWT;
        #pragma unroll
        for (int u = 0; u < NU; ++u) {
            int idx = t + u * 256;
            if (idx < GN) {
                int o = offs[u];
                float g = 0.f;
                if (o >= 0) g = gelu_exact(preg[u] + Qc[o] + ba1);
                GT[idx] = g;
            }
        }
        __syncthreads();

        // 11x11 depthwise conv, 4x4 register blocking
        float cacc[4][4];
        #pragma unroll
        for (int j = 0; j < 4; ++j)
            for (int q = 0; q < 4; ++q) cacc[j][q] = 0.f;

        #pragma unroll
        for (int iy = 0; iy < 14; ++iy) {
            float wf[16];
            const float4* gp = (const float4*)&GT[(r0 + iy) * GP] + (t & 15);
            #pragma unroll
            for (int q = 0; q < 4; ++q) {
                float4 s = gp[q];
                wf[q * 4 + 0] = s.x; wf[q * 4 + 1] = s.y;
                wf[q * 4 + 2] = s.z; wf[q * 4 + 3] = s.w;
            }
            #pragma unroll
            for (int j = 0; j < 4; ++j) {
                int dy = iy - j;
                if (dy >= 0 && dy <= 10) {
                    #pragma unroll
                    for (int dx = 0; dx < 11; ++dx) {
                        float cw = wr[dy * 11 + dx];
                        cacc[j][0] = fmaf(cw, wf[dx + 0], cacc[j][0]);
                        cacc[j][1] = fmaf(cw, wf[dx + 1], cacc[j][1]);
                        cacc[j][2] = fmaf(cw, wf[dx + 2], cacc[j][2]);
                        cacc[j][3] = fmaf(cw, wf[dx + 3], cacc[j][3]);
                    }
                }
            }
        }
        __syncthreads();  // before next k overwrites GT

        // fuse * vproj[k] * att[i,k], accumulate over k
        const float* Vc  = V + (size_t)(k * CC + c) * HWT;
        const float* cfk = conf + k * HWT;
        #pragma unroll
        for (int j = 0; j < 4; ++j) {
            int base = (y0 + r0 + j) * WW + x0 + px0;
            float4 v4 = *(const float4*)(Vc + base);
            float4 ck = *(const float4*)(cfk + base);
            sacc[j][0] = fmaf((cacc[j][0] + bdw) * v4.x, omci[j][0] * ck.x, sacc[j][0]);
            sacc[j][1] = fmaf((cacc[j][1] + bdw) * v4.y, omci[j][1] * ck.y, sacc[j][1]);
            sacc[j][2] = fmaf((cacc[j][2] + bdw) * v4.z, omci[j][2] * ck.z, sacc[j][2]);
            sacc[j][3] = fmaf((cacc[j][3] + bdw) * v4.w, omci[j][3] * ck.w, sacc[j][3]);
        }
    }

    float* Sc = S + (size_t)(i * CC + c) * HWT;
    #pragma unroll
    for (int j = 0; j < 4; ++j) {
        int base = (y0 + r0 + j) * WW + x0 + px0;
        *(float4*)(Sc + base) = make_float4(sacc[j][0], sacc[j][1], sacc[j][2], sacc[j][3]);
    }
}

// ---------------- epilogue: out = raw + projW * S + 6*pb (S aliases out, in-place per block) ----------------
__global__ __launch_bounds__(256) void k_out(
    float* so,                                  // S on input, final output on exit (aliased)
    const float* __restrict__ raw,
    const float* __restrict__ pw, const float* __restrict__ pb)
{
    const int n = blockIdx.y;
    const int og = __builtin_amdgcn_readfirstlane(threadIdx.x >> 6);
    const int pg = threadIdx.x & 63;
    const int px = blockIdx.x * 256 + pg * 4;

    const float* xb = so + (size_t)(n * CC) * HWT + px;

    float acc[16][4];
    #pragma unroll
    for (int j = 0; j < 16; ++j)
        for (int q = 0; q < 4; ++q) acc[j][q] = 0.f;

    #pragma unroll 4
    for (int c = 0; c < CC; ++c) {
        float4 x = *(const float4*)(xb + (size_t)c * HWT);
        #pragma unroll
        for (int j = 0; j < 16; ++j) {
            float w = pw[(og * 16 + j) * CC + c];   // scalar load
            acc[j][0] = fmaf(w, x.x, acc[j][0]);
            acc[j][1] = fmaf(w, x.y, acc[j][1]);
            acc[j][2] = fmaf(w, x.z, acc[j][2]);
            acc[j][3] = fmaf(w, x.w, acc[j][3]);
        }
    }

    __syncthreads();   // all reads of this block's S region complete before any write

    #pragma unroll
    for (int j = 0; j < 16; ++j) {
        int o = og * 16 + j;
        float bias = (float)NAG * pb[o];
        float4 r = *(const float4*)(raw + (size_t)(n * CC + o) * HWT + px);
        float4 w = make_float4(r.x + acc[j][0] + bias, r.y + acc[j][1] + bias,
                               r.z + acc[j][2] + bias, r.w + acc[j][3] + bias);
        *(float4*)(so + (size_t)(n * CC + o) * HWT + px) = w;
    }
}

extern "C" void kernel_launch(void* const* d_in, const int* in_sizes, int n_in,
                              void* d_out, int out_size, void* d_ws, size_t ws_size,
                              hipStream_t stream)
{
    (void)in_sizes; (void)n_in; (void)out_size; (void)ws_size;

    const float* raw   = (const float*)d_in[0];
    const float* pw_w1 = (const float*)d_in[1];
    const float* pw_b1 = (const float*)d_in[2];
    const float* bng   = (const float*)d_in[3];
    const float* bnb   = (const float*)d_in[4];
    const float* bnm   = (const float*)d_in[5];
    const float* bnv   = (const float*)d_in[6];
    const float* pw_w2 = (const float*)d_in[7];
    const float* pw_b2 = (const float*)d_in[8];
    const float* a1w   = (const float*)d_in[9];
    const float* a1b   = (const float*)d_in[10];
    const float* dww   = (const float*)d_in[11];
    const float* dwb   = (const float*)d_in[12];
    const float* vw    = (const float*)d_in[13];
    const float* vb    = (const float*)d_in[14];
    const float* pjw   = (const float*)d_in[15];
    const float* pjb   = (const float*)d_in[16];

    float* ws   = (float*)d_ws;
    float* conf = ws;                                  // 6*16384
    u32*   mm   = (u32*)(ws + NAG * HWT);              // 12 (padded to 16)
    float* P    = ws + NAG * HWT + 16;                 // 6*64*16384
    float* Q    = P + (size_t)NAG * CC * HWT;
    float* V    = Q + (size_t)NAG * CC * HWT;
    float* S    = (float*)d_out;                       // S aliases output

    dim3 blk(256);

    k_init<<<dim3(1), dim3(64), 0, stream>>>(mm);
    k_conf<<<dim3(HWT / 256, NAG), blk, 0, stream>>>(raw, pw_w1, pw_b1, bng, bnb,
                                                     bnm, bnv, pw_w2, pw_b2, conf, mm);
    k_norm<<<dim3(HWT / 256, NAG), blk, 0, stream>>>(conf, mm);
    k_pqv<<<dim3(HWT / 256, NAG, 3), blk, 0, stream>>>(raw, a1w, vw, vb, P, Q, V);
    k_main<<<dim3(4, CC, NAG), blk, 0, stream>>>(P, Q, V, conf, a1b, dww, dwb, S);
    k_out<<<dim3(HWT / 256, NAG), blk, 0, stream>>>(S, raw, pjw, pjb);
}

// Round 2
// 390.141 us; speedup vs baseline: 1.4605x; 1.4605x over previous
//
#include <hip/hip_runtime.h>
#include <math.h>

#define NAG 6
#define CC  64
#define HH  128
#define WW  128
#define HWT 16384
#define BN_EPS 1e-5f

typedef unsigned int u32;

__device__ __forceinline__ float gelu_exact(float x) {
    return 0.5f * x * (1.0f + erff(x * 0.7071067811865476f));
}

// ---------------- init min/max slots ----------------
__global__ void k_init(u32* __restrict__ mm) {
    int t = threadIdx.x;
    if (t < NAG) mm[t] = 0x7F800000u;        // +inf (min slots)
    else if (t < 2 * NAG) mm[t] = 0u;        // 0    (max slots; h2 >= 0)
}

// ---------------- confidence maps (pre-normalization) + per-agent min/max ----------------
__global__ __launch_bounds__(256) void k_conf(
    const float* __restrict__ raw,
    const float* __restrict__ w1, const float* __restrict__ b1,
    const float* __restrict__ gamma, const float* __restrict__ beta,
    const float* __restrict__ mean, const float* __restrict__ var,
    const float* __restrict__ w2, const float* __restrict__ b2,
    float* __restrict__ conf, u32* __restrict__ mm)
{
    const int n = blockIdx.y;
    const int p = blockIdx.x * 256 + threadIdx.x;
    const float* x = raw + (size_t)(n * CC) * HWT + p;

    float a[4] = {0.f, 0.f, 0.f, 0.f};
    #pragma unroll 8
    for (int c = 0; c < CC; ++c) {
        float v = x[c * HWT];
        a[0] = fmaf(w1[0 * CC + c], v, a[0]);
        a[1] = fmaf(w1[1 * CC + c], v, a[1]);
        a[2] = fmaf(w1[2 * CC + c], v, a[2]);
        a[3] = fmaf(w1[3 * CC + c], v, a[3]);
    }
    float h2 = b2[0];
    #pragma unroll
    for (int o = 0; o < 4; ++o) {
        float sc = gamma[o] * rsqrtf(var[o] + BN_EPS);
        float hb = (a[o] + b1[o] - mean[o]) * sc + beta[o];
        hb = fmaxf(hb, 0.f);
        h2 = fmaf(w2[o], hb, h2);
    }
    h2 = fmaxf(h2, 0.f);
    conf[n * HWT + p] = h2;

    float mn = h2, mx = h2;
    #pragma unroll
    for (int off = 32; off > 0; off >>= 1) {
        mn = fminf(mn, __shfl_xor(mn, off, 64));
        mx = fmaxf(mx, __shfl_xor(mx, off, 64));
    }
    __shared__ float smn[4], smx[4];
    int wid = threadIdx.x >> 6, lane = threadIdx.x & 63;
    if (lane == 0) { smn[wid] = mn; smx[wid] = mx; }
    __syncthreads();
    if (threadIdx.x == 0) {
        mn = fminf(fminf(smn[0], smn[1]), fminf(smn[2], smn[3]));
        mx = fmaxf(fmaxf(smx[0], smx[1]), fmaxf(smx[2], smx[3]));
        atomicMin(&mm[n], __float_as_uint(mn));
        atomicMax(&mm[n + NAG], __float_as_uint(mx));
    }
}

// ---------------- P = A1*raw, Q = A2*raw, W = (Vw*raw + vb) * conf_norm ----------------
// blockIdx: x = pixel block (256 px), y = agent, z = matrix (0:P, 1:Q, 2:W)
__global__ __launch_bounds__(256) void k_pqv(
    const float* __restrict__ raw, const float* __restrict__ a1w,
    const float* __restrict__ vw, const float* __restrict__ vb,
    const float* __restrict__ conf, const u32* __restrict__ mm,
    float* __restrict__ P, float* __restrict__ Q, float* __restrict__ W)
{
    const int n = blockIdx.y;
    const int m = blockIdx.z;
    const int og = __builtin_amdgcn_readfirstlane(threadIdx.x >> 6); // wave-uniform -> SGPR
    const int pg = threadIdx.x & 63;
    const int px = blockIdx.x * 256 + pg * 4;

    const float* wbase;
    int wstride;
    float* out;
    if (m == 0)      { wbase = a1w;      wstride = 2 * CC; out = P; }
    else if (m == 1) { wbase = a1w + CC; wstride = 2 * CC; out = Q; }
    else             { wbase = vw;       wstride = CC;     out = W; }

    const float* xb = raw + (size_t)(n * CC) * HWT + px;

    float acc[16][4];
    #pragma unroll
    for (int j = 0; j < 16; ++j)
        for (int q = 0; q < 4; ++q) acc[j][q] = 0.f;

    #pragma unroll 4
    for (int c = 0; c < CC; ++c) {
        float4 x = *(const float4*)(xb + (size_t)c * HWT);
        #pragma unroll
        for (int j = 0; j < 16; ++j) {
            float w = wbase[(og * 16 + j) * wstride + c];   // scalar (s_load): og uniform
            acc[j][0] = fmaf(w, x.x, acc[j][0]);
            acc[j][1] = fmaf(w, x.y, acc[j][1]);
            acc[j][2] = fmaf(w, x.z, acc[j][2]);
            acc[j][3] = fmaf(w, x.w, acc[j][3]);
        }
    }

    float4 cn = make_float4(1.f, 1.f, 1.f, 1.f);
    if (m == 2) {
        const float mn = __uint_as_float(mm[n]);
        const float mx = __uint_as_float(mm[n + NAG]);
        const float inv = 1.f / (mx - mn);
        float4 cv = *(const float4*)(conf + n * HWT + px);
        cn = make_float4((cv.x - mn) * inv, (cv.y - mn) * inv,
                         (cv.z - mn) * inv, (cv.w - mn) * inv);
    }

    #pragma unroll
    for (int j = 0; j < 16; ++j) {
        int o = og * 16 + j;
        float4 r;
        if (m == 2) {
            float b = vb[o];
            r = make_float4((acc[j][0] + b) * cn.x, (acc[j][1] + b) * cn.y,
                            (acc[j][2] + b) * cn.z, (acc[j][3] + b) * cn.w);
        } else {
            r = make_float4(acc[j][0], acc[j][1], acc[j][2], acc[j][3]);
        }
        *(float4*)(out + (size_t)(n * CC + o) * HWT + px) = r;
    }
}

// ---------------- main: S[i,c] = (sum_k dwconv11(gelu(P_i+Q_k+b)) * W_k) ----------------
// (the (1-conf_i) factor is applied in the epilogue; W_k = V_k * conf_k)
#define TS 64            // output tile side
#define GP 76            // LDS tile pitch (floats)
#define GR 74            // LDS tile rows (64 + 2*5)
#define GN (GR * GP)     // 5624
#define NU 22            // ceil(GN / 256)

__global__ __launch_bounds__(256, 3) void k_main(
    const float* __restrict__ P, const float* __restrict__ Q,
    const float* __restrict__ W, const float* __restrict__ conf,
    const u32* __restrict__ mm,
    const float* __restrict__ a1b, const float* __restrict__ dww,
    const float* __restrict__ dwb, float* __restrict__ S)
{
    const int tile = blockIdx.x;              // 0..3
    const int c    = blockIdx.y;              // 0..63
    const int i    = blockIdx.z;              // 0..5
    const int y0 = (tile >> 1) * TS;
    const int x0 = (tile & 1) * TS;
    const int t  = threadIdx.x;
    const int r0  = (t >> 4) * 4;             // thread's 4 output rows (within tile)
    const int px0 = (t & 15) * 4;             // thread's 4 output cols (within tile)

    __shared__ float GT[GN];

    const float ba1 = a1b[c];
    const float bdw = dwb[c];
    const float* wr = dww + c * 121;          // block-uniform -> scalar loads

    // preload halo'd P tile (+ a1 bias) into registers, remember global offsets
    float preg[NU];
    int   offs[NU];
    const float* Pc = P + (size_t)(i * CC + c) * HWT;
    #pragma unroll
    for (int u = 0; u < NU; ++u) {
        int idx = t + u * 256;
        int row = idx / GP, col = idx - row * GP;
        int gy = y0 + row - 5, gx = x0 + col - 5;
        bool inb = (idx < GN) && (col < GR) &&
                   (gy >= 0) && (gy < HH) && (gx >= 0) && (gx < WW);
        offs[u] = inb ? (gy * WW + gx) : -1;
        preg[u] = inb ? (Pc[gy * WW + gx] + ba1) : 0.f;
    }

    const int obase = (y0 + r0) * WW + x0 + px0;

    float sacc[4][4];
    #pragma unroll
    for (int j = 0; j < 4; ++j)
        for (int q = 0; q < 4; ++q) sacc[j][q] = 0.f;

    // prefetch Q for k=0 (invalid slots -> 0 so gelu(0)=0 gives SAME zero-padding)
    float qreg[NU];
    {
        const float* Qc = Q + (size_t)(0 * CC + c) * HWT;
        #pragma unroll
        for (int u = 0; u < NU; ++u)
            qreg[u] = (offs[u] >= 0) ? Qc[offs[u]] : 0.f;
    }

    #pragma unroll 1
    for (int k = 0; k < NAG; ++k) {
        // ---- write phase: GT = gelu(P + Q + b) (pure VALU+LDS, data already in regs)
        #pragma unroll
        for (int u = 0; u < NU; ++u) {
            int idx = t + u * 256;
            if (idx < GN) GT[idx] = gelu_exact(preg[u] + qreg[u]);
        }
        __syncthreads();

        // ---- prefetch next k's Q: latency hidden under the conv below
        if (k + 1 < NAG) {
            const float* Qc = Q + (size_t)((k + 1) * CC + c) * HWT;
            #pragma unroll
            for (int u = 0; u < NU; ++u)
                qreg[u] = (offs[u] >= 0) ? Qc[offs[u]] : 0.f;
        }

        // ---- prefetch this k's W values (consumed after the conv)
        const float* Wc = W + (size_t)(k * CC + c) * HWT;
        float4 wk[4];
        #pragma unroll
        for (int j = 0; j < 4; ++j)
            wk[j] = *(const float4*)(Wc + obase + j * WW);

        // ---- 11x11 depthwise conv, 4x4 register blocking
        float cacc[4][4];
        #pragma unroll
        for (int j = 0; j < 4; ++j)
            for (int q = 0; q < 4; ++q) cacc[j][q] = 0.f;

        #pragma unroll
        for (int iy = 0; iy < 14; ++iy) {
            float wf[16];
            const float4* gp = (const float4*)&GT[(r0 + iy) * GP] + (t & 15);
            #pragma unroll
            for (int q = 0; q < 4; ++q) {
                float4 s = gp[q];
                wf[q * 4 + 0] = s.x; wf[q * 4 + 1] = s.y;
                wf[q * 4 + 2] = s.z; wf[q * 4 + 3] = s.w;
            }
            #pragma unroll
            for (int j = 0; j < 4; ++j) {
                int dy = iy - j;
                if (dy >= 0 && dy <= 10) {
                    #pragma unroll
                    for (int dx = 0; dx < 11; ++dx) {
                        float cw = wr[dy * 11 + dx];
                        cacc[j][0] = fmaf(cw, wf[dx + 0], cacc[j][0]);
                        cacc[j][1] = fmaf(cw, wf[dx + 1], cacc[j][1]);
                        cacc[j][2] = fmaf(cw, wf[dx + 2], cacc[j][2]);
                        cacc[j][3] = fmaf(cw, wf[dx + 3], cacc[j][3]);
                    }
                }
            }
        }
        __syncthreads();  // conv reads done before next write phase

        // ---- accumulate with W_k (no GT access -> safe after barrier)
        #pragma unroll
        for (int j = 0; j < 4; ++j) {
            sacc[j][0] = fmaf(cacc[j][0] + bdw, wk[j].x, sacc[j][0]);
            sacc[j][1] = fmaf(cacc[j][1] + bdw, wk[j].y, sacc[j][1]);
            sacc[j][2] = fmaf(cacc[j][2] + bdw, wk[j].z, sacc[j][2]);
            sacc[j][3] = fmaf(cacc[j][3] + bdw, wk[j].w, sacc[j][3]);
        }
    }

    // ---- epilogue: multiply by (1 - conf_norm_i), store
    const float mn = __uint_as_float(mm[i]);
    const float mx = __uint_as_float(mm[i + NAG]);
    const float inv = 1.f / (mx - mn);
    const float* cfi = conf + i * HWT;
    float* Sc = S + (size_t)(i * CC + c) * HWT;
    #pragma unroll
    for (int j = 0; j < 4; ++j) {
        float4 cv = *(const float4*)(cfi + obase + j * WW);
        float4 r;
        r.x = sacc[j][0] * (1.f - (cv.x - mn) * inv);
        r.y = sacc[j][1] * (1.f - (cv.y - mn) * inv);
        r.z = sacc[j][2] * (1.f - (cv.z - mn) * inv);
        r.w = sacc[j][3] * (1.f - (cv.w - mn) * inv);
        *(float4*)(Sc + obase + j * WW) = r;
    }
}

// ---------------- epilogue: out = raw + projW * S + 6*pb (S aliases out, in-place per block) ----------------
__global__ __launch_bounds__(256) void k_out(
    float* so,                                  // S on input, final output on exit (aliased)
    const float* __restrict__ raw,
    const float* __restrict__ pw, const float* __restrict__ pb)
{
    const int n = blockIdx.y;
    const int og = __builtin_amdgcn_readfirstlane(threadIdx.x >> 6);
    const int pg = threadIdx.x & 63;
    const int px = blockIdx.x * 256 + pg * 4;

    const float* xb = so + (size_t)(n * CC) * HWT + px;

    float acc[16][4];
    #pragma unroll
    for (int j = 0; j < 16; ++j)
        for (int q = 0; q < 4; ++q) acc[j][q] = 0.f;

    #pragma unroll 4
    for (int c = 0; c < CC; ++c) {
        float4 x = *(const float4*)(xb + (size_t)c * HWT);
        #pragma unroll
        for (int j = 0; j < 16; ++j) {
            float w = pw[(og * 16 + j) * CC + c];   // scalar load
            acc[j][0] = fmaf(w, x.x, acc[j][0]);
            acc[j][1] = fmaf(w, x.y, acc[j][1]);
            acc[j][2] = fmaf(w, x.z, acc[j][2]);
            acc[j][3] = fmaf(w, x.w, acc[j][3]);
        }
    }

    __syncthreads();   // all reads of this block's S region complete before any write

    #pragma unroll
    for (int j = 0; j < 16; ++j) {
        int o = og * 16 + j;
        float bias = (float)NAG * pb[o];
        float4 r = *(const float4*)(raw + (size_t)(n * CC + o) * HWT + px);
        float4 w = make_float4(r.x + acc[j][0] + bias, r.y + acc[j][1] + bias,
                               r.z + acc[j][2] + bias, r.w + acc[j][3] + bias);
        *(float4*)(so + (size_t)(n * CC + o) * HWT + px) = w;
    }
}

extern "C" void kernel_launch(void* const* d_in, const int* in_sizes, int n_in,
                              void* d_out, int out_size, void* d_ws, size_t ws_size,
                              hipStream_t stream)
{
    (void)in_sizes; (void)n_in; (void)out_size; (void)ws_size;

    const float* raw   = (const float*)d_in[0];
    const float* pw_w1 = (const float*)d_in[1];
    const float* pw_b1 = (const float*)d_in[2];
    const float* bng   = (const float*)d_in[3];
    const float* bnb   = (const float*)d_in[4];
    const float* bnm   = (const float*)d_in[5];
    const float* bnv   = (const float*)d_in[6];
    const float* pw_w2 = (const float*)d_in[7];
    const float* pw_b2 = (const float*)d_in[8];
    const float* a1w   = (const float*)d_in[9];
    const float* a1b   = (const float*)d_in[10];
    const float* dww   = (const float*)d_in[11];
    const float* dwb   = (const float*)d_in[12];
    const float* vw    = (const float*)d_in[13];
    const float* vb    = (const float*)d_in[14];
    const float* pjw   = (const float*)d_in[15];
    const float* pjb   = (const float*)d_in[16];

    float* ws   = (float*)d_ws;
    float* conf = ws;                                  // 6*16384
    u32*   mm   = (u32*)(ws + NAG * HWT);              // 12 (padded to 16)
    float* P    = ws + NAG * HWT + 16;                 // 6*64*16384
    float* Q    = P + (size_t)NAG * CC * HWT;
    float* W    = Q + (size_t)NAG * CC * HWT;
    float* S    = (float*)d_out;                       // S aliases output

    dim3 blk(256);

    k_init<<<dim3(1), dim3(64), 0, stream>>>(mm);
    k_conf<<<dim3(HWT / 256, NAG), blk, 0, stream>>>(raw, pw_w1, pw_b1, bng, bnb,
                                                     bnm, bnv, pw_w2, pw_b2, conf, mm);
    k_pqv<<<dim3(HWT / 256, NAG, 3), blk, 0, stream>>>(raw, a1w, vw, vb, conf, mm, P, Q, W);
    k_main<<<dim3(4, CC, NAG), blk, 0, stream>>>(P, Q, W, conf, mm, a1b, dww, dwb, S);
    k_out<<<dim3(HWT / 256, NAG), blk, 0, stream>>>(S, raw, pjw, pjb);
}

// Round 3
// 275.295 us; speedup vs baseline: 2.0698x; 1.4172x over previous
//
#include <hip/hip_runtime.h>
#include <math.h>

#define NAG 6
#define CC  64
#define HH  128
#define WW  128
#define HWT 16384
#define BN_EPS 1e-5f

typedef unsigned int u32;

// branch-free tanh-form gelu: x * sigmoid(1.5957691*(x + 0.044715 x^3))
// exp2-folded: sigmoid arg scaled by log2(e)
__device__ __forceinline__ float gelu_fast(float x) {
    float s = x * x;
    float m = fmaf(s, -0.10294535f, -2.30226045f);   // -(2*0.79788456*log2e)*(1+0.044715 s)
    float e = __builtin_amdgcn_exp2f(x * m);          // e^{-2a}
    return x * __builtin_amdgcn_rcpf(1.0f + e);       // x * sigmoid(2a)
}

// ---------------- init min/max slots ----------------
__global__ void k_init(u32* __restrict__ mm) {
    int t = threadIdx.x;
    if (t < NAG) mm[t] = 0x7F800000u;        // +inf (min slots)
    else if (t < 2 * NAG) mm[t] = 0u;        // 0    (max slots; h2 >= 0)
}

// ---------------- confidence maps (pre-normalization) + per-agent min/max ----------------
__global__ __launch_bounds__(256) void k_conf(
    const float* __restrict__ raw,
    const float* __restrict__ w1, const float* __restrict__ b1,
    const float* __restrict__ gamma, const float* __restrict__ beta,
    const float* __restrict__ mean, const float* __restrict__ var,
    const float* __restrict__ w2, const float* __restrict__ b2,
    float* __restrict__ conf, u32* __restrict__ mm)
{
    const int n = blockIdx.y;
    const int p = blockIdx.x * 256 + threadIdx.x;
    const float* x = raw + (size_t)(n * CC) * HWT + p;

    float a[4] = {0.f, 0.f, 0.f, 0.f};
    #pragma unroll 8
    for (int c = 0; c < CC; ++c) {
        float v = x[c * HWT];
        a[0] = fmaf(w1[0 * CC + c], v, a[0]);
        a[1] = fmaf(w1[1 * CC + c], v, a[1]);
        a[2] = fmaf(w1[2 * CC + c], v, a[2]);
        a[3] = fmaf(w1[3 * CC + c], v, a[3]);
    }
    float h2 = b2[0];
    #pragma unroll
    for (int o = 0; o < 4; ++o) {
        float sc = gamma[o] * rsqrtf(var[o] + BN_EPS);
        float hb = (a[o] + b1[o] - mean[o]) * sc + beta[o];
        hb = fmaxf(hb, 0.f);
        h2 = fmaf(w2[o], hb, h2);
    }
    h2 = fmaxf(h2, 0.f);
    conf[n * HWT + p] = h2;

    float mn = h2, mx = h2;
    #pragma unroll
    for (int off = 32; off > 0; off >>= 1) {
        mn = fminf(mn, __shfl_xor(mn, off, 64));
        mx = fmaxf(mx, __shfl_xor(mx, off, 64));
    }
    __shared__ float smn[4], smx[4];
    int wid = threadIdx.x >> 6, lane = threadIdx.x & 63;
    if (lane == 0) { smn[wid] = mn; smx[wid] = mx; }
    __syncthreads();
    if (threadIdx.x == 0) {
        mn = fminf(fminf(smn[0], smn[1]), fminf(smn[2], smn[3]));
        mx = fmaxf(fmaxf(smx[0], smx[1]), fmaxf(smx[2], smx[3]));
        atomicMin(&mm[n], __float_as_uint(mn));
        atomicMax(&mm[n + NAG], __float_as_uint(mx));
    }
}

// ---------------- P = A1*raw, Q = A2*raw, W = (Vw*raw + vb) * conf_norm ----------------
// 512 threads: 8 wave-groups x 8 output rows; blockIdx: x=px block, y=agent, z=matrix
__global__ __launch_bounds__(512) void k_pqv(
    const float* __restrict__ raw, const float* __restrict__ a1w,
    const float* __restrict__ vw, const float* __restrict__ vb,
    const float* __restrict__ conf, const u32* __restrict__ mm,
    float* __restrict__ P, float* __restrict__ Q, float* __restrict__ W)
{
    const int n = blockIdx.y;
    const int m = blockIdx.z;
    const int og = __builtin_amdgcn_readfirstlane(threadIdx.x >> 6); // wave-uniform
    const int pg = threadIdx.x & 63;
    const int px = blockIdx.x * 256 + pg * 4;

    const float* wbase;
    int wstride;
    float* out;
    if (m == 0)      { wbase = a1w;      wstride = 2 * CC; out = P; }
    else if (m == 1) { wbase = a1w + CC; wstride = 2 * CC; out = Q; }
    else             { wbase = vw;       wstride = CC;     out = W; }

    const float* xb = raw + (size_t)(n * CC) * HWT + px;

    float acc[8][4];
    #pragma unroll
    for (int j = 0; j < 8; ++j)
        for (int q = 0; q < 4; ++q) acc[j][q] = 0.f;

    #pragma unroll 4
    for (int c = 0; c < CC; ++c) {
        float4 x = *(const float4*)(xb + (size_t)c * HWT);
        #pragma unroll
        for (int j = 0; j < 8; ++j) {
            float w = wbase[(og * 8 + j) * wstride + c];   // scalar load (og uniform)
            acc[j][0] = fmaf(w, x.x, acc[j][0]);
            acc[j][1] = fmaf(w, x.y, acc[j][1]);
            acc[j][2] = fmaf(w, x.z, acc[j][2]);
            acc[j][3] = fmaf(w, x.w, acc[j][3]);
        }
    }

    float4 cn = make_float4(1.f, 1.f, 1.f, 1.f);
    if (m == 2) {
        const float mn = __uint_as_float(mm[n]);
        const float mx = __uint_as_float(mm[n + NAG]);
        const float inv = 1.f / (mx - mn);
        float4 cv = *(const float4*)(conf + n * HWT + px);
        cn = make_float4((cv.x - mn) * inv, (cv.y - mn) * inv,
                         (cv.z - mn) * inv, (cv.w - mn) * inv);
    }

    #pragma unroll
    for (int j = 0; j < 8; ++j) {
        int o = og * 8 + j;
        float4 r;
        if (m == 2) {
            float b = vb[o];
            r = make_float4((acc[j][0] + b) * cn.x, (acc[j][1] + b) * cn.y,
                            (acc[j][2] + b) * cn.z, (acc[j][3] + b) * cn.w);
        } else {
            r = make_float4(acc[j][0], acc[j][1], acc[j][2], acc[j][3]);
        }
        *(float4*)(out + (size_t)(n * CC + o) * HWT + px) = r;
    }
}

// ---------------- main: S[i,c] = (sum_k dwconv11(gelu(P_i+Q_k+b)) * W_k) ----------------
#define TS 64            // output tile side
#define GP 76            // LDS tile pitch (floats)
#define GR 74            // LDS tile rows (64 + 2*5)
#define GN (GR * GP)     // 5624
#define NU 22            // ceil(GN / 256)

__global__ __launch_bounds__(256, 3) void k_main(
    const float* __restrict__ P, const float* __restrict__ Q,
    const float* __restrict__ W, const float* __restrict__ conf,
    const u32* __restrict__ mm,
    const float* __restrict__ a1b, const float* __restrict__ dww,
    const float* __restrict__ dwb, float* __restrict__ S)
{
    const int tile = blockIdx.x;              // 0..3
    const int c    = blockIdx.y;              // 0..63
    const int i    = blockIdx.z;              // 0..5
    const int y0 = (tile >> 1) * TS;
    const int x0 = (tile & 1) * TS;
    const int t  = threadIdx.x;
    const int r0  = (t >> 4) * 4;
    const int px0 = (t & 15) * 4;

    __shared__ float GT[GN];

    const float ba1 = a1b[c];
    const float bdw = dwb[c];
    const float* wr = dww + c * 121;          // block-uniform -> scalar loads

    // preload halo'd P tile (+ a1 bias) into registers, remember global offsets
    float preg[NU];
    int   offs[NU];
    const float* Pc = P + (size_t)(i * CC + c) * HWT;
    #pragma unroll
    for (int u = 0; u < NU; ++u) {
        int idx = t + u * 256;
        int row = idx / GP, col = idx - row * GP;
        int gy = y0 + row - 5, gx = x0 + col - 5;
        bool inb = (idx < GN) && (col < GR) &&
                   (gy >= 0) && (gy < HH) && (gx >= 0) && (gx < WW);
        offs[u] = inb ? (gy * WW + gx) : -1;
        preg[u] = inb ? (Pc[gy * WW + gx] + ba1) : 0.f;
    }

    const int obase = (y0 + r0) * WW + x0 + px0;

    float sacc[4][4];
    #pragma unroll
    for (int j = 0; j < 4; ++j)
        for (int q = 0; q < 4; ++q) sacc[j][q] = 0.f;

    // prefetch Q for k=0 (invalid slots -> 0 so gelu(0)=0 gives SAME zero-padding)
    float qreg[NU];
    {
        const float* Qc = Q + (size_t)(0 * CC + c) * HWT;
        #pragma unroll
        for (int u = 0; u < NU; ++u)
            qreg[u] = (offs[u] >= 0) ? Qc[offs[u]] : 0.f;
    }

    #pragma unroll 1
    for (int k = 0; k < NAG; ++k) {
        // ---- prefetch this k's W values early: consumed only after the conv
        const float* Wc = W + (size_t)(k * CC + c) * HWT;
        float4 wk[4];
        #pragma unroll
        for (int j = 0; j < 4; ++j)
            wk[j] = *(const float4*)(Wc + obase + j * WW);

        // ---- write phase: GT = gelu(P + Q + b) (data already in regs)
        #pragma unroll
        for (int u = 0; u < NU - 1; ++u)
            GT[t + u * 256] = gelu_fast(preg[u] + qreg[u]);
        {
            int idx = t + (NU - 1) * 256;
            if (idx < GN) GT[idx] = gelu_fast(preg[NU - 1] + qreg[NU - 1]);
        }
        __syncthreads();

        // ---- prefetch next k's Q: latency hidden under the conv below
        if (k + 1 < NAG) {
            const float* Qc = Q + (size_t)((k + 1) * CC + c) * HWT;
            #pragma unroll
            for (int u = 0; u < NU; ++u)
                qreg[u] = (offs[u] >= 0) ? Qc[offs[u]] : 0.f;
        }

        // ---- 11x11 depthwise conv, 4x4 register blocking
        float cacc[4][4];
        #pragma unroll
        for (int j = 0; j < 4; ++j)
            for (int q = 0; q < 4; ++q) cacc[j][q] = 0.f;

        #pragma unroll
        for (int iy = 0; iy < 14; ++iy) {
            float wf[16];
            const float4* gp = (const float4*)&GT[(r0 + iy) * GP] + (t & 15);
            #pragma unroll
            for (int q = 0; q < 4; ++q) {
                float4 s = gp[q];
                wf[q * 4 + 0] = s.x; wf[q * 4 + 1] = s.y;
                wf[q * 4 + 2] = s.z; wf[q * 4 + 3] = s.w;
            }
            #pragma unroll
            for (int j = 0; j < 4; ++j) {
                int dy = iy - j;
                if (dy >= 0 && dy <= 10) {
                    #pragma unroll
                    for (int dx = 0; dx < 11; ++dx) {
                        float cw = wr[dy * 11 + dx];
                        cacc[j][0] = fmaf(cw, wf[dx + 0], cacc[j][0]);
                        cacc[j][1] = fmaf(cw, wf[dx + 1], cacc[j][1]);
                        cacc[j][2] = fmaf(cw, wf[dx + 2], cacc[j][2]);
                        cacc[j][3] = fmaf(cw, wf[dx + 3], cacc[j][3]);
                    }
                }
            }
        }
        __syncthreads();  // conv reads done before next write phase

        // ---- accumulate with W_k
        #pragma unroll
        for (int j = 0; j < 4; ++j) {
            sacc[j][0] = fmaf(cacc[j][0] + bdw, wk[j].x, sacc[j][0]);
            sacc[j][1] = fmaf(cacc[j][1] + bdw, wk[j].y, sacc[j][1]);
            sacc[j][2] = fmaf(cacc[j][2] + bdw, wk[j].z, sacc[j][2]);
            sacc[j][3] = fmaf(cacc[j][3] + bdw, wk[j].w, sacc[j][3]);
        }
    }

    // ---- epilogue: multiply by (1 - conf_norm_i), store
    const float mn = __uint_as_float(mm[i]);
    const float mx = __uint_as_float(mm[i + NAG]);
    const float inv = 1.f / (mx - mn);
    const float* cfi = conf + i * HWT;
    float* Sc = S + (size_t)(i * CC + c) * HWT;
    #pragma unroll
    for (int j = 0; j < 4; ++j) {
        float4 cv = *(const float4*)(cfi + obase + j * WW);
        float4 r;
        r.x = sacc[j][0] * (1.f - (cv.x - mn) * inv);
        r.y = sacc[j][1] * (1.f - (cv.y - mn) * inv);
        r.z = sacc[j][2] * (1.f - (cv.z - mn) * inv);
        r.w = sacc[j][3] * (1.f - (cv.w - mn) * inv);
        *(float4*)(Sc + obase + j * WW) = r;
    }
}

// ---------------- epilogue: out = raw + projW * S + 6*pb (S aliases out) ----------------
// 512 threads: 8 wave-groups x 8 output rows; block reads all c of its px slice,
// syncs, then writes its own px slice -> self-contained in-place update.
__global__ __launch_bounds__(512) void k_out(
    float* so,
    const float* __restrict__ raw,
    const float* __restrict__ pw, const float* __restrict__ pb)
{
    const int n = blockIdx.y;
    const int og = __builtin_amdgcn_readfirstlane(threadIdx.x >> 6);
    const int pg = threadIdx.x & 63;
    const int px = blockIdx.x * 256 + pg * 4;

    const float* xb = so + (size_t)(n * CC) * HWT + px;

    float acc[8][4];
    #pragma unroll
    for (int j = 0; j < 8; ++j)
        for (int q = 0; q < 4; ++q) acc[j][q] = 0.f;

    #pragma unroll 4
    for (int c = 0; c < CC; ++c) {
        float4 x = *(const float4*)(xb + (size_t)c * HWT);
        #pragma unroll
        for (int j = 0; j < 8; ++j) {
            float w = pw[(og * 8 + j) * CC + c];   // scalar load
            acc[j][0] = fmaf(w, x.x, acc[j][0]);
            acc[j][1] = fmaf(w, x.y, acc[j][1]);
            acc[j][2] = fmaf(w, x.z, acc[j][2]);
            acc[j][3] = fmaf(w, x.w, acc[j][3]);
        }
    }

    __syncthreads();   // all reads of this block's S region complete before any write

    #pragma unroll
    for (int j = 0; j < 8; ++j) {
        int o = og * 8 + j;
        float bias = (float)NAG * pb[o];
        float4 r = *(const float4*)(raw + (size_t)(n * CC + o) * HWT + px);
        float4 w = make_float4(r.x + acc[j][0] + bias, r.y + acc[j][1] + bias,
                               r.z + acc[j][2] + bias, r.w + acc[j][3] + bias);
        *(float4*)(so + (size_t)(n * CC + o) * HWT + px) = w;
    }
}

extern "C" void kernel_launch(void* const* d_in, const int* in_sizes, int n_in,
                              void* d_out, int out_size, void* d_ws, size_t ws_size,
                              hipStream_t stream)
{
    (void)in_sizes; (void)n_in; (void)out_size; (void)ws_size;

    const float* raw   = (const float*)d_in[0];
    const float* pw_w1 = (const float*)d_in[1];
    const float* pw_b1 = (const float*)d_in[2];
    const float* bng   = (const float*)d_in[3];
    const float* bnb   = (const float*)d_in[4];
    const float* bnm   = (const float*)d_in[5];
    const float* bnv   = (const float*)d_in[6];
    const float* pw_w2 = (const float*)d_in[7];
    const float* pw_b2 = (const float*)d_in[8];
    const float* a1w   = (const float*)d_in[9];
    const float* a1b   = (const float*)d_in[10];
    const float* dww   = (const float*)d_in[11];
    const float* dwb   = (const float*)d_in[12];
    const float* vw    = (const float*)d_in[13];
    const float* vb    = (const float*)d_in[14];
    const float* pjw   = (const float*)d_in[15];
    const float* pjb   = (const float*)d_in[16];

    float* ws   = (float*)d_ws;
    float* conf = ws;                                  // 6*16384
    u32*   mm   = (u32*)(ws + NAG * HWT);              // 12 (padded to 16)
    float* P    = ws + NAG * HWT + 16;                 // 6*64*16384
    float* Q    = P + (size_t)NAG * CC * HWT;
    float* W    = Q + (size_t)NAG * CC * HWT;
    float* S    = (float*)d_out;                       // S aliases output

    k_init<<<dim3(1), dim3(64), 0, stream>>>(mm);
    k_conf<<<dim3(HWT / 256, NAG), dim3(256), 0, stream>>>(raw, pw_w1, pw_b1, bng, bnb,
                                                           bnm, bnv, pw_w2, pw_b2, conf, mm);
    k_pqv<<<dim3(HWT / 256, NAG, 3), dim3(512), 0, stream>>>(raw, a1w, vw, vb, conf, mm, P, Q, W);
    k_main<<<dim3(4, CC, NAG), dim3(256), 0, stream>>>(P, Q, W, conf, mm, a1b, dww, dwb, S);
    k_out<<<dim3(HWT / 256, NAG), dim3(512), 0, stream>>>(S, raw, pjw, pjb);
}